// Round 1
// baseline (114.809 us; speedup 1.0000x reference)
//
#include <hip/hip_runtime.h>
#include <hip/hip_bf16.h>

typedef __bf16 bf16_t;
typedef bf16_t bf16x8 __attribute__((ext_vector_type(8)));
typedef bf16_t bf16x4 __attribute__((ext_vector_type(4)));
typedef float  floatx4 __attribute__((ext_vector_type(4)));

#define NROWS 65536
#define NCENT 512
#define NDIM  128
#define BM    128
#define BN    128
#define PITCH 136   // 128 + 8 bf16 pad: keeps 16B alignment, breaks 256B bank stride

__global__ __launch_bounds__(256, 2)
void kmeans_min_dist_kernel(const float* __restrict__ z,
                            const float* __restrict__ mu,
                            float* __restrict__ out)
{
    __shared__ bf16_t tile[BM * PITCH];   // A tile first, then reused for mu chunks
    __shared__ float z2s[BM];
    __shared__ float m2s[BN];
    __shared__ float red[256];
    __shared__ unsigned rowmin_u[BM];

    const int tid  = threadIdx.x;
    const int lane = tid & 63;
    const int w    = tid >> 6;
    const int wy   = w >> 1;    // row half (0..1)
    const int wx   = w & 1;     // col half (0..1)
    const int quad = lane >> 4; // 0..3
    const int l16  = lane & 15;

    // ---- stage A: 128 rows of z, fp32 -> bf16, flat coalesced float4 loads ----
    const float4* zsrc = (const float4*)(z + (size_t)blockIdx.x * BM * NDIM);
#pragma unroll
    for (int k = 0; k < 16; ++k) {
        int q = k * 256 + tid;          // float4 index 0..4095
        float4 v = zsrc[q];
        int r = q >> 5;                 // 32 float4 per 128-float row
        int c = (q & 31) << 2;
        bf16x4 pk = { (bf16_t)v.x, (bf16_t)v.y, (bf16_t)v.z, (bf16_t)v.w };
        *(bf16x4*)&tile[r * PITCH + c] = pk;
    }
    if (tid < BM) rowmin_u[tid] = 0x7f800000u;  // +inf bits
    __syncthreads();

    // ---- z2 from staged bf16 (consistent with MFMA inputs) ----
    {
        int r = tid >> 1, h = tid & 1;
        const bf16_t* src = &tile[r * PITCH + h * 64];
        float s = 0.f;
#pragma unroll
        for (int v8 = 0; v8 < 8; ++v8) {
            bf16x8 x = *(const bf16x8*)(src + v8 * 8);
#pragma unroll
            for (int e = 0; e < 8; ++e) { float f = (float)x[e]; s = fmaf(f, f, s); }
        }
        red[tid] = s;
    }
    __syncthreads();
    if (tid < BM) z2s[tid] = red[2 * tid] + red[2 * tid + 1];
    __syncthreads();

    // ---- hoist A fragments + z2 into registers (reused for all 4 chunks) ----
    bf16x8 afrag[4][4];
#pragma unroll
    for (int i = 0; i < 4; ++i)
#pragma unroll
        for (int kk = 0; kk < 4; ++kk)
            afrag[i][kk] = *(const bf16x8*)&tile[(wy*64 + i*16 + l16) * PITCH + kk*32 + quad*8];

    float z2r[4][4];
#pragma unroll
    for (int i = 0; i < 4; ++i)
#pragma unroll
        for (int r = 0; r < 4; ++r)
            z2r[i][r] = z2s[wy*64 + i*16 + quad*4 + r];

    float rmin[4][4];
#pragma unroll
    for (int i = 0; i < 4; ++i)
#pragma unroll
        for (int r = 0; r < 4; ++r) rmin[i][r] = 3.0e38f;

    // ---- loop over 4 centroid chunks of 128 ----
    for (int ch = 0; ch < NCENT / BN; ++ch) {
        __syncthreads();  // all reads of tile/m2s from previous chunk done
        const float4* msrc = (const float4*)(mu + (size_t)ch * BN * NDIM);
#pragma unroll
        for (int k = 0; k < 16; ++k) {
            int q = k * 256 + tid;
            float4 v = msrc[q];
            int r = q >> 5;
            int c = (q & 31) << 2;
            bf16x4 pk = { (bf16_t)v.x, (bf16_t)v.y, (bf16_t)v.z, (bf16_t)v.w };
            *(bf16x4*)&tile[r * PITCH + c] = pk;
        }
        __syncthreads();
        {
            int r = tid >> 1, h = tid & 1;
            const bf16_t* src = &tile[r * PITCH + h * 64];
            float s = 0.f;
#pragma unroll
            for (int v8 = 0; v8 < 8; ++v8) {
                bf16x8 x = *(const bf16x8*)(src + v8 * 8);
#pragma unroll
                for (int e = 0; e < 8; ++e) { float f = (float)x[e]; s = fmaf(f, f, s); }
            }
            red[tid] = s;
        }
        __syncthreads();
        if (tid < BN) m2s[tid] = red[2 * tid] + red[2 * tid + 1];
        __syncthreads();

        // ---- MFMA: each wave computes its 64x64 tile, K=128 ----
        floatx4 acc[4][4];
#pragma unroll
        for (int i = 0; i < 4; ++i)
#pragma unroll
            for (int j = 0; j < 4; ++j)
                acc[i][j] = (floatx4){0.f, 0.f, 0.f, 0.f};

#pragma unroll
        for (int kk = 0; kk < 4; ++kk) {
            bf16x8 bfr[4];
#pragma unroll
            for (int j = 0; j < 4; ++j)
                bfr[j] = *(const bf16x8*)&tile[(wx*64 + j*16 + l16) * PITCH + kk*32 + quad*8];
#pragma unroll
            for (int i = 0; i < 4; ++i)
#pragma unroll
                for (int j = 0; j < 4; ++j)
                    acc[i][j] = __builtin_amdgcn_mfma_f32_16x16x32_bf16(
                        afrag[i][kk], bfr[j], acc[i][j], 0, 0, 0);
        }

        // ---- epilogue: d2 -> dist -> running per-row min (per lane) ----
#pragma unroll
        for (int j = 0; j < 4; ++j) {
            float m2v = m2s[wx*64 + j*16 + l16];
#pragma unroll
            for (int i = 0; i < 4; ++i)
#pragma unroll
                for (int r = 0; r < 4; ++r) {
                    float d2 = fmaf(-2.f, acc[i][j][r], z2r[i][r] + m2v);
                    d2 = fmaxf(d2, 0.f);
                    rmin[i][r] = fminf(rmin[i][r], sqrtf(d2));
                }
        }
    }

    // ---- reduce min over the 16 lanes sharing a row-set, merge waves via LDS ----
#pragma unroll
    for (int i = 0; i < 4; ++i)
#pragma unroll
        for (int r = 0; r < 4; ++r) {
            float v = rmin[i][r];
            v = fminf(v, __shfl_xor(v, 1));
            v = fminf(v, __shfl_xor(v, 2));
            v = fminf(v, __shfl_xor(v, 4));
            v = fminf(v, __shfl_xor(v, 8));
            if (l16 == 0) {
                int row = wy*64 + i*16 + quad*4 + r;
                atomicMin(&rowmin_u[row], __float_as_uint(v));  // dist >= 0: uint order == float order
            }
        }
    __syncthreads();

    // ---- block sum of 128 row-min distances, one atomicAdd ----
    red[tid] = (tid < BM) ? __uint_as_float(rowmin_u[tid]) : 0.f;
    __syncthreads();
    if (tid < 64) {
        float v = red[tid] + red[tid + 64] + ((tid + 128 < 256) ? 0.f : 0.f);
        v += 0.f; // rows 0..127 covered by red[tid] + red[tid+64]
#pragma unroll
        for (int off = 32; off; off >>= 1) v += __shfl_down(v, off);
        if (tid == 0) atomicAdd(out, v * (1.0f / 65536.0f));
    }
}

extern "C" void kernel_launch(void* const* d_in, const int* in_sizes, int n_in,
                              void* d_out, int out_size, void* d_ws, size_t ws_size,
                              hipStream_t stream) {
    const float* z  = (const float*)d_in[0];
    const float* mu = (const float*)d_in[1];
    float* out = (float*)d_out;
    hipMemsetAsync(out, 0, sizeof(float), stream);  // harness poisons d_out with 0xAA
    kmeans_min_dist_kernel<<<dim3(NROWS / BM), dim3(256), 0, stream>>>(z, mu, out);
}

// Round 2
// 101.652 us; speedup vs baseline: 1.1294x; 1.1294x over previous
//
#include <hip/hip_runtime.h>
#include <hip/hip_bf16.h>

typedef __bf16 bf16_t;
typedef bf16_t bf16x8 __attribute__((ext_vector_type(8)));
typedef bf16_t bf16x4 __attribute__((ext_vector_type(4)));
typedef float  floatx4 __attribute__((ext_vector_type(4)));

#define NROWS 65536
#define NCENT 512
#define NDIM  128
#define BM    64
#define ZPITCH 136          // 128 + 8 bf16 pad: 16B-aligned rows, 2-way (free) bank aliasing
#define NCHUNK 8
#define CHUNK_COLS 64

// d_ws layout: [0, 131072) mu bf16 frag-major; [131072, 133120) h2 = 0.5*|mu|^2 float[512]
// frag-major element (col,k) -> c*8192 + g*2048 + kk*512 + quad*128 + c16*8 + e
//   where col = c*64 + g*16 + c16, k = kk*32 + quad*8 + e
// This is exactly the order a wave's B-fragment ds_read_b128 lanes consume, so
// global_load_lds (wave-uniform base + lane*16B) lands it with zero conflicts.

__device__ __forceinline__ void gload_lds16(const bf16_t* g, bf16_t* l) {
    __builtin_amdgcn_global_load_lds(
        (const __attribute__((address_space(1))) unsigned int*)g,
        (__attribute__((address_space(3))) unsigned int*)l,
        16, 0, 0);
}

__global__ __launch_bounds__(256)
void mu_pack_kernel(const float* __restrict__ mu, bf16_t* __restrict__ ws_mu,
                    float* __restrict__ ws_h2)
{
    const int tid = threadIdx.x;
    const int col_local = tid >> 5;     // 8 cols per block
    const int j = tid & 31;             // 32 threads per col, 4 floats each
    const int col = blockIdx.x * 8 + col_local;
    const float4 v = *(const float4*)(mu + col * NDIM + j * 4);
    bf16x4 pk = {(bf16_t)v.x, (bf16_t)v.y, (bf16_t)v.z, (bf16_t)v.w};
    const int k0 = j * 4;
    const int kk = k0 >> 5, quad = (k0 >> 3) & 3, e0 = k0 & 7;
    const int c = col >> 6, g = (col >> 4) & 3, c16 = col & 15;
    const int addr = c * 8192 + g * 2048 + kk * 512 + quad * 128 + c16 * 8 + e0;
    *(bf16x4*)(ws_mu + addr) = pk;
    // h2 from the bf16-rounded values (consistent with MFMA dot)
    float f0 = (float)pk[0], f1 = (float)pk[1], f2 = (float)pk[2], f3 = (float)pk[3];
    float s = f0 * f0 + f1 * f1 + f2 * f2 + f3 * f3;
    s += __shfl_xor(s, 1);  s += __shfl_xor(s, 2);  s += __shfl_xor(s, 4);
    s += __shfl_xor(s, 8);  s += __shfl_xor(s, 16);
    if (j == 0) ws_h2[col] = 0.5f * s;
}

__global__ __launch_bounds__(256, 4)
void kmeans_main(const float* __restrict__ z, const bf16_t* __restrict__ ws_mu,
                 const float* __restrict__ ws_h2, float* __restrict__ out)
{
    __shared__ bf16_t ztile[BM * ZPITCH];        // 17408 B
    __shared__ bf16_t mubuf[CHUNK_COLS * NDIM];  // 16384 B, frag-major, global_load_lds dest
    __shared__ float h2s[NCENT];                 // 2048 B
    __shared__ float z2s[BM];                    // 256 B
    __shared__ float red[128];                   // 512 B
    __shared__ float wmax[4][BM];                // 1024 B   -> total ~37.6 KB, 4 blocks/CU

    const int tid  = threadIdx.x;
    const int lane = tid & 63;
    const int w    = tid >> 6;
    const int quad = lane >> 4;
    const int l16  = lane & 15;

    // ---- stage z tile: fp32 -> bf16, b128 LDS writes (2-way bank aliasing = free) ----
    const float4* zsrc = (const float4*)(z + (size_t)blockIdx.x * BM * NDIM);
#pragma unroll
    for (int it = 0; it < 4; ++it) {
        int q8 = it * 256 + tid;          // 8-float unit, 1024 total
        float4 va = zsrc[q8 * 2];
        float4 vb = zsrc[q8 * 2 + 1];
        int r = q8 >> 4, c8 = (q8 & 15) << 3;
        bf16x8 pk = {(bf16_t)va.x, (bf16_t)va.y, (bf16_t)va.z, (bf16_t)va.w,
                     (bf16_t)vb.x, (bf16_t)vb.y, (bf16_t)vb.z, (bf16_t)vb.w};
        *(bf16x8*)&ztile[r * ZPITCH + c8] = pk;
    }
    h2s[tid] = ws_h2[tid];
    h2s[tid + 256] = ws_h2[tid + 256];
    __syncthreads();

    // ---- z2 per row from staged bf16 (consistent with MFMA inputs) ----
    if (tid < 128) {
        int r = tid >> 1, h = tid & 1;
        const bf16_t* srcp = &ztile[r * ZPITCH + h * 64];
        float s = 0.f;
#pragma unroll
        for (int v8 = 0; v8 < 8; ++v8) {
            bf16x8 x = *(const bf16x8*)(srcp + v8 * 8);
#pragma unroll
            for (int e = 0; e < 8; ++e) { float f = (float)x[e]; s = fmaf(f, f, s); }
        }
        red[tid] = s;
    }
    __syncthreads();
    if (tid < 64) z2s[tid] = red[2 * tid] + red[2 * tid + 1];

    float tmax[4][4];
#pragma unroll
    for (int i = 0; i < 4; ++i)
#pragma unroll
        for (int r = 0; r < 4; ++r) tmax[i][r] = -3.0e38f;

    // ---- 8 chunks of 64 centroids; mu staged direct-to-LDS, no cvt, no VGPR trip ----
#pragma unroll 1
    for (int c = 0; c < NCHUNK; ++c) {
        __syncthreads();   // prior chunk's B reads (and z2/red phase) complete
#pragma unroll
        for (int it = 0; it < 4; ++it) {
            int idx = it * 256 + tid;                       // 16B units, 1024 total
            gload_lds16(ws_mu + c * 8192 + idx * 8, &mubuf[idx * 8]);
        }
        __syncthreads();   // drains vmcnt -> staging visible

        // B frags: wave w owns cols c*64 + w*16 + l16 (conflict-free contiguous reads)
        bf16x8 bfr[4];
#pragma unroll
        for (int kk = 0; kk < 4; ++kk)
            bfr[kk] = *(const bf16x8*)&mubuf[w * 2048 + kk * 512 + quad * 128 + l16 * 8];

        float h2v = h2s[c * 64 + w * 16 + l16];

#pragma unroll
        for (int i = 0; i < 4; ++i) {
            floatx4 acc = (floatx4){0.f, 0.f, 0.f, 0.f};
#pragma unroll
            for (int kk = 0; kk < 4; ++kk) {
                bf16x8 afr = *(const bf16x8*)&ztile[(i * 16 + l16) * ZPITCH + kk * 32 + quad * 8];
                acc = __builtin_amdgcn_mfma_f32_16x16x32_bf16(afr, bfr[kk], acc, 0, 0, 0);
            }
            // deferred-sqrt epilogue: track max(dot - 0.5*m2); 2 VALU ops per element
#pragma unroll
            for (int r = 0; r < 4; ++r)
                tmax[i][r] = fmaxf(tmax[i][r], acc[r] - h2v);
        }
    }

    // ---- per-row max over the 16 cols this lane saw, then across waves ----
#pragma unroll
    for (int i = 0; i < 4; ++i)
#pragma unroll
        for (int r = 0; r < 4; ++r) {
            float v = tmax[i][r];
            v = fmaxf(v, __shfl_xor(v, 1));
            v = fmaxf(v, __shfl_xor(v, 2));
            v = fmaxf(v, __shfl_xor(v, 4));
            v = fmaxf(v, __shfl_xor(v, 8));
            if (l16 == 0) wmax[w][i * 16 + quad * 4 + r] = v;
        }
    __syncthreads();

    // ---- one sqrt per row, block sum, one atomic ----
    if (tid < 64) {
        float m = fmaxf(fmaxf(wmax[0][tid], wmax[1][tid]),
                        fmaxf(wmax[2][tid], wmax[3][tid]));
        float d2 = z2s[tid] - 2.0f * m;
        float v = sqrtf(fmaxf(d2, 0.f));
#pragma unroll
        for (int off = 32; off; off >>= 1) v += __shfl_down(v, off);
        if (tid == 0) atomicAdd(out, v * (1.0f / 65536.0f));
    }
}

extern "C" void kernel_launch(void* const* d_in, const int* in_sizes, int n_in,
                              void* d_out, int out_size, void* d_ws, size_t ws_size,
                              hipStream_t stream) {
    const float* z  = (const float*)d_in[0];
    const float* mu = (const float*)d_in[1];
    float* out = (float*)d_out;
    bf16_t* ws_mu = (bf16_t*)d_ws;
    float* ws_h2 = (float*)((char*)d_ws + 131072);
    hipMemsetAsync(out, 0, sizeof(float), stream);   // harness poisons d_out with 0xAA
    mu_pack_kernel<<<dim3(64), dim3(256), 0, stream>>>(mu, ws_mu, ws_h2);
    kmeans_main<<<dim3(NROWS / BM), dim3(256), 0, stream>>>(z, ws_mu, ws_h2, out);
}

// Round 3
// 89.188 us; speedup vs baseline: 1.2873x; 1.1398x over previous
//
#include <hip/hip_runtime.h>
#include <hip/hip_bf16.h>

typedef __bf16 bf16_t;
typedef bf16_t bf16x8 __attribute__((ext_vector_type(8)));
typedef bf16_t bf16x4 __attribute__((ext_vector_type(4)));
typedef float  floatx4 __attribute__((ext_vector_type(4)));

#define NROWS 65536
#define NCENT 512
#define NDIM  128
#define NBLK  256
#define TROWS 64
#define NTILE (NROWS / (NBLK * TROWS))   // 4
#define ZPITCH 136   // 128 + 8 bf16 pad

// d_ws: [0,131072) mu bf16 frag-major; [131072,133120) h2 = 0.5*|mu|^2 float[512]
// frag-major (col,k): addr = j*2048 + kk*512 + quad*128 + l16*8 + e
//   col = j*16+l16, k = kk*32+quad*8+e  -> B-frag ds_read_b128 is 1KB contiguous/wave

__device__ __forceinline__ void gload_lds16(const bf16_t* g, bf16_t* l) {
    __builtin_amdgcn_global_load_lds(
        (const __attribute__((address_space(1))) unsigned int*)g,
        (__attribute__((address_space(3))) unsigned int*)l,
        16, 0, 0);
}

__global__ __launch_bounds__(256)
void mu_pack_kernel(const float* __restrict__ mu, bf16_t* __restrict__ ws_mu,
                    float* __restrict__ ws_h2)
{
    const int tid = threadIdx.x;
    const int col_local = tid >> 5;     // 8 cols per block
    const int j = tid & 31;             // 32 threads per col, 4 floats each
    const int col = blockIdx.x * 8 + col_local;
    const float4 v = *(const float4*)(mu + col * NDIM + j * 4);
    bf16x4 pk = {(bf16_t)v.x, (bf16_t)v.y, (bf16_t)v.z, (bf16_t)v.w};
    const int k0 = j * 4;
    const int kk = k0 >> 5, quad = (k0 >> 3) & 3, e0 = k0 & 7;
    const int c = col >> 6, g = (col >> 4) & 3, c16 = col & 15;
    const int addr = c * 8192 + g * 2048 + kk * 512 + quad * 128 + c16 * 8 + e0;
    *(bf16x4*)(ws_mu + addr) = pk;
    float f0 = (float)pk[0], f1 = (float)pk[1], f2 = (float)pk[2], f3 = (float)pk[3];
    float s = f0 * f0 + f1 * f1 + f2 * f2 + f3 * f3;
    s += __shfl_xor(s, 1);  s += __shfl_xor(s, 2);  s += __shfl_xor(s, 4);
    s += __shfl_xor(s, 8);  s += __shfl_xor(s, 16);
    if (j == 0) ws_h2[col] = 0.5f * s;
}

__global__ __launch_bounds__(512, 2)
void kmeans_main(const float* __restrict__ z, const bf16_t* __restrict__ ws_mu,
                 const float* __restrict__ ws_h2, float* __restrict__ out)
{
    __shared__ bf16_t muf[NCENT * NDIM];       // 131072 B, frag-major, resident all kernel
    __shared__ bf16_t ztile[TROWS * ZPITCH];   // 17408 B
    __shared__ float h2s[NCENT];               // 2048 B
    __shared__ float z2s[TROWS];               // 256 B
    __shared__ float rmx[TROWS][2];            // 512 B    -> ~151 KB total, 1 block/CU

    const int tid  = threadIdx.x;
    const int lane = tid & 63;
    const int w    = tid >> 6;
    const int quad = lane >> 4;
    const int l16  = lane & 15;
    const int s    = w >> 1;     // row strip 0..3 (16 rows each)
    const int h    = w & 1;      // column half: groups h*16 .. h*16+15

    // ---- prefetch z tile 0 into VGPRs (coalesced: 32B per thread) ----
    float4 pf[4];
    {
        const float4* zsrc = (const float4*)(z + (size_t)blockIdx.x * TROWS * NDIM);
#pragma unroll
        for (int i = 0; i < 2; ++i) {
            int q8 = i * 512 + tid;
            pf[2*i]     = zsrc[q8 * 2];
            pf[2*i + 1] = zsrc[q8 * 2 + 1];
        }
    }

    // ---- stage ALL of mu (128 KB bf16) direct to LDS, once ----
#pragma unroll
    for (int i = 0; i < 16; ++i) {
        int idx = i * 512 + tid;                 // 16B units
        gload_lds16(ws_mu + idx * 8, &muf[idx * 8]);
    }
    h2s[tid] = ws_h2[tid];

    float fsum = 0.f;

    for (int t = 0; t < NTILE; ++t) {
        // ---- stage ztile (cvt fp32->bf16) + per-row z2 from rounded values ----
#pragma unroll
        for (int i = 0; i < 2; ++i) {
            int q8 = i * 512 + tid;              // 8-float unit; 16 units per row
            float4 va = pf[2*i], vb = pf[2*i + 1];
            int r = q8 >> 4, c8 = (q8 & 15) << 3;
            bf16x8 pk = {(bf16_t)va.x, (bf16_t)va.y, (bf16_t)va.z, (bf16_t)va.w,
                         (bf16_t)vb.x, (bf16_t)vb.y, (bf16_t)vb.z, (bf16_t)vb.w};
            *(bf16x8*)&ztile[r * ZPITCH + c8] = pk;
            float ss = 0.f;
#pragma unroll
            for (int e = 0; e < 8; ++e) { float f = (float)pk[e]; ss = fmaf(f, f, ss); }
            ss += __shfl_xor(ss, 1); ss += __shfl_xor(ss, 2);
            ss += __shfl_xor(ss, 4); ss += __shfl_xor(ss, 8);
            if (l16 == 0) z2s[r] = ss;           // 16 lanes per row, lane group-leader writes
        }
        __syncthreads();   // B1: ztile+z2s visible; also drains mu gload (t==0)

        // ---- issue prefetch of tile t+1 (hidden under the MFMA phase) ----
        if (t + 1 < NTILE) {
            const float4* zsrc = (const float4*)(z + ((size_t)(t + 1) * NBLK + blockIdx.x) * TROWS * NDIM);
#pragma unroll
            for (int i = 0; i < 2; ++i) {
                int q8 = i * 512 + tid;
                pf[2*i]     = zsrc[q8 * 2];
                pf[2*i + 1] = zsrc[q8 * 2 + 1];
            }
        }

        // ---- A fragments for this wave's 16-row strip ----
        bf16x8 afr[4];
#pragma unroll
        for (int kk = 0; kk < 4; ++kk)
            afr[kk] = *(const bf16x8*)&ztile[(s * 16 + l16) * ZPITCH + kk * 32 + quad * 8];

        float tm[4] = {-3.0e38f, -3.0e38f, -3.0e38f, -3.0e38f};
#pragma unroll
        for (int j2 = 0; j2 < 16; ++j2) {
            const int j = h * 16 + j2;
            bf16x8 bfr[4];
#pragma unroll
            for (int kk = 0; kk < 4; ++kk)
                bfr[kk] = *(const bf16x8*)&muf[((j * 4 + kk) * 4 + quad) * 128 + l16 * 8];
            floatx4 acc = (floatx4){0.f, 0.f, 0.f, 0.f};
#pragma unroll
            for (int kk = 0; kk < 4; ++kk)
                acc = __builtin_amdgcn_mfma_f32_16x16x32_bf16(afr[kk], bfr[kk], acc, 0, 0, 0);
            float h2v = h2s[j * 16 + l16];
#pragma unroll
            for (int r = 0; r < 4; ++r)
                tm[r] = fmaxf(tm[r], acc[r] - h2v);   // deferred-sqrt: track max(dot - m2/2)
        }

        // ---- per-row max over this wave's 16 cols; publish per column-half ----
#pragma unroll
        for (int r = 0; r < 4; ++r) {
            float v = tm[r];
            v = fmaxf(v, __shfl_xor(v, 1));
            v = fmaxf(v, __shfl_xor(v, 2));
            v = fmaxf(v, __shfl_xor(v, 4));
            v = fmaxf(v, __shfl_xor(v, 8));
            if (l16 == 0) rmx[s * 16 + quad * 4 + r][h] = v;
        }
        __syncthreads();   // B2: rmx visible

        if (tid < TROWS) {
            float m  = fmaxf(rmx[tid][0], rmx[tid][1]);
            float d2 = z2s[tid] - 2.0f * m;
            fsum += sqrtf(fmaxf(d2, 0.f));    // one sqrt per row
        }
        __syncthreads();   // B3: protect rmx/z2s/ztile for next tile
    }

    // ---- wave-0 holds all row sums; reduce + one atomic per block ----
    if (w == 0) {
        float v = fsum;
#pragma unroll
        for (int off = 32; off; off >>= 1) v += __shfl_down(v, off);
        if (tid == 0) atomicAdd(out, v * (1.0f / 65536.0f));
    }
}

extern "C" void kernel_launch(void* const* d_in, const int* in_sizes, int n_in,
                              void* d_out, int out_size, void* d_ws, size_t ws_size,
                              hipStream_t stream) {
    const float* z  = (const float*)d_in[0];
    const float* mu = (const float*)d_in[1];
    float* out = (float*)d_out;
    bf16_t* ws_mu = (bf16_t*)d_ws;
    float* ws_h2 = (float*)((char*)d_ws + 131072);
    hipMemsetAsync(out, 0, sizeof(float), stream);   // d_out is poisoned 0xAA
    mu_pack_kernel<<<dim3(64), dim3(256), 0, stream>>>(mu, ws_mu, ws_h2);
    kmeans_main<<<dim3(NBLK), dim3(512), 0, stream>>>(z, ws_mu, ws_h2, out);
}